// Round 4
// baseline (909.413 us; speedup 1.0000x reference)
//
#include <hip/hip_runtime.h>
#include <hip/hip_bf16.h>

// GCN: 3x GCNConv(H=64) + global mean pool + linear head.
// Round 3 -> 4: persistent fused layer kernels (grid-stride over nodes).
// Weights loaded into LDS once per block (coalesced); per-node __syncthreads
// removed (wave-local LDS row broadcast); conflict-free GEMM reads;
// layer-1 gather+transform fused into one kernel.

#define WS_ALIGN(x) (((x) + 255) & ~size_t(255))

__global__ __launch_bounds__(256) void k_init(int n, int g, int* degi, int* cursor,
                                              float* gsum, float* gcnt) {
    int i = blockIdx.x * blockDim.x + threadIdx.x;
    if (i < n) { degi[i] = 1; cursor[i] = 0; }
    if (i < g) { gsum[i] = 0.f; gcnt[i] = 0.f; }
}

__global__ __launch_bounds__(256) void k_deg(int e, const int* __restrict__ dst,
                                             int* __restrict__ degi) {
    int i = blockIdx.x * blockDim.x + threadIdx.x;
    if (i < e) atomicAdd(&degi[dst[i]], 1);
}

__global__ __launch_bounds__(256) void k_dinv(int n, const int* __restrict__ degi,
                                              const float* __restrict__ x,
                                              float* __restrict__ dinv,
                                              float* __restrict__ xs) {
    int i = blockIdx.x * blockDim.x + threadIdx.x;
    if (i >= n) return;
    float di = 1.0f / sqrtf((float)degi[i]);   // deg >= 1 always
    dinv[i] = di;
    xs[i] = x[i] * di;
}

// ---- CSR build (in-degree exclusive scan + cursor scatter) ----
__global__ __launch_bounds__(256) void k_scan1(int n, const int* __restrict__ degi,
                                               int* __restrict__ start,
                                               int* __restrict__ psum) {
    __shared__ int sd[256];
    int tid = threadIdx.x;
    int i0 = blockIdx.x * 1024 + tid * 4;
    int a = (i0 + 0 < n) ? degi[i0 + 0] - 1 : 0;
    int b = (i0 + 1 < n) ? degi[i0 + 1] - 1 : 0;
    int c = (i0 + 2 < n) ? degi[i0 + 2] - 1 : 0;
    int d = (i0 + 3 < n) ? degi[i0 + 3] - 1 : 0;
    int tsum = a + b + c + d;
    sd[tid] = tsum;
    __syncthreads();
    for (int off = 1; off < 256; off <<= 1) {
        int v = (tid >= off) ? sd[tid - off] : 0;
        __syncthreads();
        sd[tid] += v;
        __syncthreads();
    }
    int excl = sd[tid] - tsum;
    if (i0 + 0 < n) start[i0 + 0] = excl;
    if (i0 + 1 < n) start[i0 + 1] = excl + a;
    if (i0 + 2 < n) start[i0 + 2] = excl + a + b;
    if (i0 + 3 < n) start[i0 + 3] = excl + a + b + c;
    if (tid == 255) psum[blockIdx.x] = sd[255];
}

__global__ __launch_bounds__(256) void k_scan2(int nchunks, int* __restrict__ psum) {
    __shared__ int sd[256];
    int tid = threadIdx.x;
    int i0 = tid * 4;
    int a = (i0 + 0 < nchunks) ? psum[i0 + 0] : 0;
    int b = (i0 + 1 < nchunks) ? psum[i0 + 1] : 0;
    int c = (i0 + 2 < nchunks) ? psum[i0 + 2] : 0;
    int d = (i0 + 3 < nchunks) ? psum[i0 + 3] : 0;
    int tsum = a + b + c + d;
    sd[tid] = tsum;
    __syncthreads();
    for (int off = 1; off < 256; off <<= 1) {
        int v = (tid >= off) ? sd[tid - off] : 0;
        __syncthreads();
        sd[tid] += v;
        __syncthreads();
    }
    int excl = sd[tid] - tsum;
    if (i0 + 0 < nchunks) psum[i0 + 0] = excl;
    if (i0 + 1 < nchunks) psum[i0 + 1] = excl + a;
    if (i0 + 2 < nchunks) psum[i0 + 2] = excl + a + b;
    if (i0 + 3 < nchunks) psum[i0 + 3] = excl + a + b + c;
}

__global__ __launch_bounds__(256) void k_scan3(int n, int e, int* __restrict__ start,
                                               const int* __restrict__ psum) {
    int i = blockIdx.x * blockDim.x + threadIdx.x;
    if (i < n) start[i] += psum[i >> 10];
    if (i == n) start[n] = e;
}

__global__ __launch_bounds__(256) void k_scatter(int e, const int* __restrict__ src,
                                                 const int* __restrict__ dst,
                                                 const int* __restrict__ start,
                                                 int* __restrict__ cursor,
                                                 int* __restrict__ csr) {
    int i = blockIdx.x * blockDim.x + threadIdx.x;
    if (i >= e) return;
    int v = dst[i];
    int pos = start[v] + atomicAdd(&cursor[v], 1);
    csr[pos] = src[i];
}

// ---- layer 1 fused (rank-1): per node, gather scalar + transform row ----
// hs1[v][j] = relu(((sum_in xs[u] + xs[v]) * dinv[v]) * w1[j] + b1[j]) * dinv[v]
__global__ __launch_bounds__(256, 8) void k_layer1(int n, const int* __restrict__ start,
                                                   const int* __restrict__ csr,
                                                   const float* __restrict__ xs,
                                                   const float* __restrict__ dinv,
                                                   const float* __restrict__ w1,
                                                   const float* __restrict__ b1,
                                                   float* __restrict__ hs_out) {
    int tid = threadIdx.x;
    int r = tid >> 6, lane = tid & 63;
    float w1r = w1[lane], b1r = b1[lane];
    int wid = blockIdx.x * 4 + r;
    int stride = gridDim.x * 4;
    for (int v = wid; v < n; v += stride) {
        int s0 = start[v], s1 = start[v + 1];
        float acc = 0.f;
        for (int k = s0 + lane; k < s1; k += 64) acc += xs[csr[k]];
#pragma unroll
        for (int m = 32; m > 0; m >>= 1) acc += __shfl_xor(acc, m, 64);
        float dv = dinv[v];
        float s = (acc + xs[v]) * dv;
        hs_out[(size_t)v * 64 + lane] = fmaxf(s * w1r + b1r, 0.f) * dv;
    }
}

// ---- persistent fused layer: gather(+self) -> GEMM(w) -> relu -> *dinv ----
// one wave per node iteration; weights in LDS once per block; row broadcast via
// wave-local LDS slot (no block barrier in the loop).
__global__ __launch_bounds__(256, 8) void k_layer(int n, const int* __restrict__ start,
                                                  const int* __restrict__ csr,
                                                  const float* __restrict__ hs_in,
                                                  const float* __restrict__ dinv,
                                                  const float* __restrict__ w,
                                                  const float* __restrict__ b,
                                                  float* __restrict__ hs_out) {
    __shared__ float ws[64 * 64];    // [k][j], coalesced load, conflict-free read
    __shared__ float rowl[4][64];    // per-wave row slot (wave-local use only)
    int tid = threadIdx.x;
    for (int k = tid; k < 64 * 64; k += 256) ws[k] = w[k];
    __syncthreads();
    int r = tid >> 6, lane = tid & 63;
    float breg = b[lane];
    int wid = blockIdx.x * 4 + r;
    int stride = gridDim.x * 4;
    for (int v = wid; v < n; v += stride) {
        int s0 = start[v], s1 = start[v + 1];
        float dv = dinv[v];
        float a0 = hs_in[(size_t)v * 64 + lane];
        float a1 = 0.f, a2 = 0.f, a3 = 0.f, a4 = 0.f, a5 = 0.f, a6 = 0.f, a7 = 0.f;
        for (int base = s0; base < s1; base += 64) {
            int k = base + lane;
            int u = (k < s1) ? csr[k] : 0;
            int m = s1 - base; if (m > 64) m = 64;
            int t = 0;
            for (; t + 8 <= m; t += 8) {
                int u0 = __shfl(u, t, 64),     u1 = __shfl(u, t + 1, 64);
                int u2 = __shfl(u, t + 2, 64), u3 = __shfl(u, t + 3, 64);
                int u4 = __shfl(u, t + 4, 64), u5 = __shfl(u, t + 5, 64);
                int u6 = __shfl(u, t + 6, 64), u7 = __shfl(u, t + 7, 64);
                a0 += hs_in[(size_t)u0 * 64 + lane]; a1 += hs_in[(size_t)u1 * 64 + lane];
                a2 += hs_in[(size_t)u2 * 64 + lane]; a3 += hs_in[(size_t)u3 * 64 + lane];
                a4 += hs_in[(size_t)u4 * 64 + lane]; a5 += hs_in[(size_t)u5 * 64 + lane];
                a6 += hs_in[(size_t)u6 * 64 + lane]; a7 += hs_in[(size_t)u7 * 64 + lane];
            }
            for (; t < m; ++t) {
                int u0 = __shfl(u, t, 64);
                a0 += hs_in[(size_t)u0 * 64 + lane];
            }
        }
        rowl[r][lane] = ((((a0 + a1) + (a2 + a3)) + ((a4 + a5) + (a6 + a7)))) * dv;
        // wave-local RAW on LDS: ordered by lgkmcnt, no barrier needed
        float acc = breg;
#pragma unroll
        for (int k = 0; k < 64; ++k) acc += rowl[r][k] * ws[k * 64 + lane];
        hs_out[(size_t)v * 64 + lane] = fmaxf(acc, 0.f) * dv;
    }
}

// final persistent fused layer: gather -> GEMM(w3) -> relu -> dot(fcw) -> dots[v]
__global__ __launch_bounds__(256, 8) void k_layer_final(int n, const int* __restrict__ start,
                                                        const int* __restrict__ csr,
                                                        const float* __restrict__ hs_in,
                                                        const float* __restrict__ dinv,
                                                        const float* __restrict__ w,
                                                        const float* __restrict__ b,
                                                        const float* __restrict__ fcw,
                                                        float* __restrict__ dots) {
    __shared__ float ws[64 * 64];
    __shared__ float rowl[4][64];
    int tid = threadIdx.x;
    for (int k = tid; k < 64 * 64; k += 256) ws[k] = w[k];
    __syncthreads();
    int r = tid >> 6, lane = tid & 63;
    float breg = b[lane];
    float freg = fcw[lane];
    int wid = blockIdx.x * 4 + r;
    int stride = gridDim.x * 4;
    for (int v = wid; v < n; v += stride) {
        int s0 = start[v], s1 = start[v + 1];
        float dv = dinv[v];
        float a0 = hs_in[(size_t)v * 64 + lane];
        float a1 = 0.f, a2 = 0.f, a3 = 0.f, a4 = 0.f, a5 = 0.f, a6 = 0.f, a7 = 0.f;
        for (int base = s0; base < s1; base += 64) {
            int k = base + lane;
            int u = (k < s1) ? csr[k] : 0;
            int m = s1 - base; if (m > 64) m = 64;
            int t = 0;
            for (; t + 8 <= m; t += 8) {
                int u0 = __shfl(u, t, 64),     u1 = __shfl(u, t + 1, 64);
                int u2 = __shfl(u, t + 2, 64), u3 = __shfl(u, t + 3, 64);
                int u4 = __shfl(u, t + 4, 64), u5 = __shfl(u, t + 5, 64);
                int u6 = __shfl(u, t + 6, 64), u7 = __shfl(u, t + 7, 64);
                a0 += hs_in[(size_t)u0 * 64 + lane]; a1 += hs_in[(size_t)u1 * 64 + lane];
                a2 += hs_in[(size_t)u2 * 64 + lane]; a3 += hs_in[(size_t)u3 * 64 + lane];
                a4 += hs_in[(size_t)u4 * 64 + lane]; a5 += hs_in[(size_t)u5 * 64 + lane];
                a6 += hs_in[(size_t)u6 * 64 + lane]; a7 += hs_in[(size_t)u7 * 64 + lane];
            }
            for (; t < m; ++t) {
                int u0 = __shfl(u, t, 64);
                a0 += hs_in[(size_t)u0 * 64 + lane];
            }
        }
        rowl[r][lane] = ((((a0 + a1) + (a2 + a3)) + ((a4 + a5) + (a6 + a7)))) * dv;
        float acc = breg;
#pragma unroll
        for (int k = 0; k < 64; ++k) acc += rowl[r][k] * ws[k * 64 + lane];
        float val = fmaxf(acc, 0.f) * freg;
#pragma unroll
        for (int o = 32; o > 0; o >>= 1) val += __shfl_xor(val, o, 64);
        if (lane == 0) dots[v] = val;
    }
}

// pooled accumulation: LDS-binned segmented reduce over sorted batch.
__global__ __launch_bounds__(256) void k_pool(int n, const float* __restrict__ dots,
                                              const int* __restrict__ batch,
                                              float* __restrict__ gsum,
                                              float* __restrict__ gcnt) {
    __shared__ float ls[64], lc[64];
    __shared__ int gmin_s;
    int tid = threadIdx.x;
    int i0 = blockIdx.x * 1024;
    if (tid == 0) gmin_s = batch[i0];
    if (tid < 64) { ls[tid] = 0.f; lc[tid] = 0.f; }
    __syncthreads();
    int gmin = gmin_s;
#pragma unroll
    for (int c = 0; c < 4; ++c) {
        int i = i0 + c * 256 + tid;
        if (i < n) {
            int g = batch[i];
            float d = dots[i];
            int rr = g - gmin;
            if (rr < 64) {
                atomicAdd(&ls[rr], d);
                atomicAdd(&lc[rr], 1.f);
            } else {
                atomicAdd(&gsum[g], d);
                atomicAdd(&gcnt[g], 1.f);
            }
        }
    }
    __syncthreads();
    if (tid < 64 && lc[tid] != 0.f) {
        atomicAdd(&gsum[gmin + tid], ls[tid]);
        atomicAdd(&gcnt[gmin + tid], lc[tid]);
    }
}

__global__ __launch_bounds__(256) void k_out(int g, const float* __restrict__ gsum,
                                             const float* __restrict__ gcnt,
                                             const float* __restrict__ fcb,
                                             float* __restrict__ out) {
    int i = blockIdx.x * blockDim.x + threadIdx.x;
    if (i < g) out[i] = gsum[i] / fmaxf(gcnt[i], 1.f) + fcb[0];
}

extern "C" void kernel_launch(void* const* d_in, const int* in_sizes, int n_in,
                              void* d_out, int out_size, void* d_ws, size_t ws_size,
                              hipStream_t stream) {
    const float* x    = (const float*)d_in[0];
    const int*   ei   = (const int*)d_in[1];
    const int*   batch= (const int*)d_in[2];
    const float* w1   = (const float*)d_in[3];
    const float* b1   = (const float*)d_in[4];
    const float* w2   = (const float*)d_in[5];
    const float* b2   = (const float*)d_in[6];
    const float* w3   = (const float*)d_in[7];
    const float* b3   = (const float*)d_in[8];
    const float* fcw  = (const float*)d_in[9];
    const float* fcb  = (const float*)d_in[10];
    float* out = (float*)d_out;

    const int N = in_sizes[0];
    const int E = in_sizes[1] / 2;
    const int G = out_size;
    const int H = 64;

    const int* src = ei;
    const int* dst = ei + E;

    char* p = (char*)d_ws;
    int*   degi   = (int*)p;   p += WS_ALIGN(sizeof(int) * N);
    int*   cursor = (int*)p;   p += WS_ALIGN(sizeof(int) * N);
    int*   start  = (int*)p;   p += WS_ALIGN(sizeof(int) * (N + 1));
    int*   psum   = (int*)p;   p += WS_ALIGN(sizeof(int) * 1024);
    int*   csr    = (int*)p;   p += WS_ALIGN(sizeof(int) * (size_t)E);
    float* dinv   = (float*)p; p += WS_ALIGN(sizeof(float) * N);
    float* xs     = (float*)p; p += WS_ALIGN(sizeof(float) * N);
    float* bufA   = (float*)p; p += WS_ALIGN(sizeof(float) * (size_t)N * H);
    float* bufB   = (float*)p; p += WS_ALIGN(sizeof(float) * (size_t)N * H);
    float* dots   = (float*)p; p += WS_ALIGN(sizeof(float) * N);
    float* gsum   = (float*)p; p += WS_ALIGN(sizeof(float) * G);
    float* gcnt   = (float*)p; p += WS_ALIGN(sizeof(float) * G);

    const int B = 256;
    int gridN    = (N + B - 1) / B;
    int gridE    = (E + B - 1) / B;
    int gridG    = (G + B - 1) / B;
    int gridInit = ((N > G ? N : G) + B - 1) / B;
    int nchunks  = (N + 1023) / 1024;
    int gridS3   = (N + 1 + B - 1) / B;
    int gridPool = (N + 1023) / 1024;
    int gridPers = 2048;                 // persistent: 8 blocks/CU x 256 CU
    if (gridPers * 4 > N) gridPers = (N + 3) / 4;

    k_init<<<gridInit, B, 0, stream>>>(N, G, degi, cursor, gsum, gcnt);
    k_deg<<<gridE, B, 0, stream>>>(E, dst, degi);
    k_dinv<<<gridN, B, 0, stream>>>(N, degi, x, dinv, xs);
    k_scan1<<<nchunks, B, 0, stream>>>(N, degi, start, psum);
    k_scan2<<<1, B, 0, stream>>>(nchunks, psum);
    k_scan3<<<gridS3, B, 0, stream>>>(N, E, start, psum);
    k_scatter<<<gridE, B, 0, stream>>>(E, src, dst, start, cursor, csr);
    // layer 1 (rank-1, fused)
    k_layer1<<<gridPers, B, 0, stream>>>(N, start, csr, xs, dinv, w1, b1, bufA);
    // layer 2 fused: gather(hs1) + GEMM(w2) -> hs2
    k_layer<<<gridPers, B, 0, stream>>>(N, start, csr, bufA, dinv, w2, b2, bufB);
    // layer 3 fused: gather(hs2) + GEMM(w3) + relu + fc-dot -> dots
    k_layer_final<<<gridPers, B, 0, stream>>>(N, start, csr, bufB, dinv, w3, b3, fcw, dots);
    // pooling + head
    k_pool<<<gridPool, B, 0, stream>>>(N, dots, batch, gsum, gcnt);
    k_out<<<gridG, B, 0, stream>>>(G, gsum, gcnt, fcb, out);
}